// Round 2
// baseline (854.240 us; speedup 1.0000x reference)
//
#include <hip/hip_runtime.h>
#include <hip/hip_bf16.h>

#define EDGES   640000
#define NNODES  50000
#define MDIM    128
#define HDIM    64
#define XSTR    36    // padded LDS stride (floats) for f32 staging kernels

typedef __attribute__((ext_vector_type(8))) short bshort8;  // 8 bf16 = 4 VGPRs
typedef __attribute__((ext_vector_type(4))) float f32x4;    // MFMA acc

__device__ __forceinline__ short f2bf(float f) {
    __hip_bfloat16 h = __float2bfloat16(f);
    return *reinterpret_cast<short*>(&h);
}

// exact-gelu via Abramowitz-Stegun 7.1.26 erf approx (|err| < 1.5e-7)
__device__ __forceinline__ float gelu_fast(float h) {
    const float x  = h * 0.70710678118654752f;
    const float ax = fabsf(x);
    const float t  = __builtin_amdgcn_rcpf(fmaf(0.3275911f, ax, 1.0f));
    float p = fmaf(1.061405429f, t, -1.453152027f);
    p = fmaf(p, t,  1.421413741f);
    p = fmaf(p, t, -0.284496736f);
    p = fmaf(p, t,  0.254829592f);
    p *= t;
    const float e = __expf(-x * x);
    float er = fmaf(-p, e, 1.0f);
    er = (x < 0.0f) ? -er : er;
    return 0.5f * h * (1.0f + er);
}

// ---------------- K0: pack W1 message-half into bf16 MFMA B-fragment layout (bpack),
//                  and W1 feature-half transposed f32 (w1dt) for kg_nodes.
__global__ void k0_prep(const float* __restrict__ w1,
                        short* __restrict__ bpack, float* __restrict__ w1dt) {
    const int i = blockIdx.x * 256 + threadIdx.x;   // 0..16383
    if (i < 8192) {
        const int ii   = i & 7;
        const int lane = (i >> 3) & 63;
        const int jtkc = i >> 9;            // kc*4 + jt
        const int kc = jtkc >> 2, jt = jtkc & 3;
        const int j = jt * 16 + (lane & 15);
        const int k = kc * 32 + (lane >> 4) * 8 + ii;
        bpack[i] = f2bf(w1[j * 256 + k]);
    } else if (i < 16384) {
        const int t = i - 8192;             // w1dt[k][j] = W1[j][128+k]
        const int k = t >> 6, j = t & 63;
        w1dt[t] = w1[j * 256 + 128 + k];
    }
}

// ---------------- KHIST: per-node in-degree
__global__ void khist(const int* __restrict__ tgt, int* __restrict__ counts) {
    const int e = blockIdx.x * 256 + threadIdx.x;
    if (e < EDGES) atomicAdd(&counts[tgt[e]], 1);
}

// ---------------- KG: g[n][j] = b1[j] + sum_k feats[n][k]*W1d[j][k]  (f32 FMA, lane-per-node)
__global__ __launch_bounds__(256, 4) void kg_nodes(
    const float* __restrict__ feats, const float* __restrict__ w1dt,
    const float* __restrict__ b1, float* __restrict__ g)
{
    __shared__ float xs[4][64 * XSTR];
    const int wv = threadIdx.x >> 6, L = threadIdx.x & 63;
    const long base = ((long)blockIdx.x * 4 + wv) * 64;
    float* xb = xs[wv];
    float h[HDIM];
#pragma unroll
    for (int j = 0; j < HDIM; ++j) h[j] = 0.0f;
    const int gq = L >> 3, sub = L & 7;
    for (int c = 0; c < 4; ++c) {
        const int col0 = c * 32;
#pragma unroll
        for (int r = 0; r < 8; ++r) {
            long row = base + gq + 8 * r;
            if (row > NNODES - 1) row = NNODES - 1;
            float4 v = *(const float4*)(feats + row * MDIM + col0 + sub * 4);
            *(float4*)(xb + (gq + 8 * r) * XSTR + sub * 4) = v;
        }
        __syncthreads();
        for (int k4 = 0; k4 < 8; ++k4) {
            const float4 xv = *(const float4*)(xb + L * XSTR + 4 * k4);
            const float* colw = w1dt + (c * 32 + 4 * k4) * HDIM;
            const float xa[4] = {xv.x, xv.y, xv.z, xv.w};
#pragma unroll
            for (int kk = 0; kk < 4; ++kk) {
                const float xk = xa[kk];
#pragma unroll
                for (int j = 0; j < HDIM; ++j)
                    h[j] = fmaf(colw[kk * HDIM + j], xk, h[j]);
            }
        }
        __syncthreads();
    }
    const long row = base + L;
    if (row < NNODES) {
        float* gp = g + row * HDIM;
#pragma unroll
        for (int j4 = 0; j4 < 16; ++j4) {
            float4 b4 = *(const float4*)(b1 + 4 * j4);
            float4 o;
            o.x = h[4 * j4 + 0] + b4.x; o.y = h[4 * j4 + 1] + b4.y;
            o.z = h[4 * j4 + 2] + b4.z; o.w = h[4 * j4 + 3] + b4.w;
            *(float4*)(gp + 4 * j4) = o;
        }
    }
}

// ---------------- CSR build (unchanged)
__global__ void kscan_local(const int* __restrict__ counts, int* __restrict__ offsets,
                            int* __restrict__ blocksums) {
    __shared__ int s[256];
    const int tid = threadIdx.x;
    const int i = blockIdx.x * 256 + tid;
    int v = (i < NNODES) ? counts[i] : 0;
    s[tid] = v;
    __syncthreads();
    for (int d = 1; d < 256; d <<= 1) {
        int t = (tid >= d) ? s[tid - d] : 0;
        __syncthreads();
        s[tid] += t;
        __syncthreads();
    }
    if (i < NNODES) offsets[i] = s[tid];
    if (tid == 255) blocksums[blockIdx.x] = s[255];
}

__global__ void kscan_blk(int* __restrict__ blocksums, int nblk) {
    __shared__ int s[256];
    const int tid = threadIdx.x;
    int v = (tid < nblk) ? blocksums[tid] : 0;
    s[tid] = v;
    __syncthreads();
    for (int d = 1; d < 256; d <<= 1) {
        int t = (tid >= d) ? s[tid - d] : 0;
        __syncthreads();
        s[tid] += t;
        __syncthreads();
    }
    if (tid < nblk) blocksums[tid] = s[tid] - v;
}

__global__ void kscan_fix(int* __restrict__ offsets, const int* __restrict__ blocksums,
                          const int* __restrict__ counts, int* __restrict__ cursor) {
    const int i = blockIdx.x * 256 + threadIdx.x;
    if (i < NNODES) {
        const int incl = offsets[i] + blocksums[i >> 8];
        offsets[i] = incl;
        cursor[i] = incl - counts[i];
    }
}

__global__ void kscatter(const int* __restrict__ tgt, int* __restrict__ cursor,
                         int* __restrict__ eidx) {
    const int e = blockIdx.x * 256 + threadIdx.x;
    if (e < EDGES) {
        const int pos = atomicAdd(&cursor[tgt[e]], 1);
        eidx[pos] = e;
    }
}

// ---------------- KFUSED v2: wave-per-node, ZERO LDS.
// Lane (n,quad) owns row n's quad-segment (32 f32 in v[8]); after MFMA+epilogue it
// fetches its own row's weight w_n (4 shfls + 2 selects) and accumulates w_n*v into
// persistent pacc[32]. The output-column transpose happens ONCE per wave via a
// 4-round reduce-scatter across each 16-lane group (30 shfls), after which each lane
// owns 2 unique output columns -> fused divide + LayerNorm + store.
__global__ __launch_bounds__(256, 4) void kfused(
    const float* __restrict__ msgs, const int* __restrict__ eidx,
    const int* __restrict__ offsets, const short* __restrict__ bpack,
    const float* __restrict__ g, const float* __restrict__ w2,
    const float* __restrict__ gamma, const float* __restrict__ beta,
    float* __restrict__ out)
{
    const int wv = threadIdx.x >> 6, L = threadIdx.x & 63;
    const int node = blockIdx.x * 4 + wv;
    if (node >= NNODES) return;
    const int end = offsets[node];
    const int beg = (node == 0) ? 0 : offsets[node - 1];
    const int m = end - beg;

    const int n = L & 15, quad = L >> 4;
    const bshort8* bp = (const bshort8*)bpack;

    // per-wave constants: w2 row and the node's g row (uniform across all edges)
    float w2v[4], gv[4];
    const float* gp = g + (long)node * HDIM;
#pragma unroll
    for (int jt = 0; jt < 4; ++jt) {
        w2v[jt] = w2[jt * 16 + n];
        gv[jt]  = gp[jt * 16 + n];
    }

    // persistent: partial sums for this lane's 32 columns (cols kc*32+quad*8+u)
    float4 pacc[8];
#pragma unroll
    for (int p = 0; p < 8; ++p) pacc[p] = (float4){0.f, 0.f, 0.f, 0.f};
    float swl = 0.0f;

    const int srcl = (n >> 2) << 4;   // lane holding w for slot n (quad group n>>2)

    for (int t0 = 0; t0 < m; t0 += 16) {
        const int sn = t0 + n;
        const int eid = eidx[beg + ((sn < m) ? sn : 0)];   // pads clamp to slot 0 (L1-hot)
        const float* rp = msgs + (long)eid * MDIM + quad * 8;

        // row n, this quad's 8-float segment of each 32-col chunk (exactly the A-frag data)
        float4 v[8];
#pragma unroll
        for (int kc = 0; kc < 4; ++kc) {
            v[2 * kc]     = *(const float4*)(rp + kc * 32);
            v[2 * kc + 1] = *(const float4*)(rp + kc * 32 + 4);
        }

        // MFMA: H[16,64] = bf16(tile) @ W1m^T
        f32x4 hacc[4];
#pragma unroll
        for (int jt = 0; jt < 4; ++jt) hacc[jt] = (f32x4){0.f, 0.f, 0.f, 0.f};
#pragma unroll
        for (int kc = 0; kc < 4; ++kc) {
            const float4 va = v[2 * kc], vb = v[2 * kc + 1];
            bshort8 a;
            a[0] = f2bf(va.x); a[1] = f2bf(va.y); a[2] = f2bf(va.z); a[3] = f2bf(va.w);
            a[4] = f2bf(vb.x); a[5] = f2bf(vb.y); a[6] = f2bf(vb.z); a[7] = f2bf(vb.w);
#pragma unroll
            for (int jt = 0; jt < 4; ++jt)
                hacc[jt] = __builtin_amdgcn_mfma_f32_16x16x32_bf16(a, bp[(kc * 4 + jt) * 64 + L], hacc[jt], 0, 0, 0);
        }

        // epilogue: lane holds h[slot = quad*4+r][j = jt*16+n]
        float wq[4];
#pragma unroll
        for (int r = 0; r < 4; ++r) {
            float raw = 0.0f;
#pragma unroll
            for (int jt = 0; jt < 4; ++jt) {
                const float hj = hacc[jt][r] + gv[jt];
                raw = fmaf(gelu_fast(hj), w2v[jt], raw);
            }
#pragma unroll
            for (int off = 1; off < 16; off <<= 1)
                raw += __shfl_xor(raw, off, 64);
            const int slot = t0 + quad * 4 + r;
            wq[r] = (slot < m) ? __builtin_amdgcn_rcpf(1.0f + __expf(-raw)) : 0.0f;
        }

        // weight of THIS lane's row n: slot n lives in quad group n>>2, reg n&3
        const float ta = __shfl(wq[0], srcl, 64);
        const float tb = __shfl(wq[1], srcl, 64);
        const float tc = __shfl(wq[2], srcl, 64);
        const float td = __shfl(wq[3], srcl, 64);
        const float t01 = (n & 1) ? tb : ta;
        const float t23 = (n & 1) ? td : tc;
        const float wn  = (n & 2) ? t23 : t01;   // 0 for padded slots
        swl += wn;

        // accumulate into this lane's own columns — no LDS, no transpose here
#pragma unroll
        for (int p = 0; p < 8; ++p) {
            pacc[p].x = fmaf(v[p].x, wn, pacc[p].x);
            pacc[p].y = fmaf(v[p].y, wn, pacc[p].y);
            pacc[p].z = fmaf(v[p].z, wn, pacc[p].z);
            pacc[p].w = fmaf(v[p].w, wn, pacc[p].w);
        }
    }

    // ---- reduce-scatter pacc over the 16 lanes of each quad group (sum over rows n)
    // local index l = p*4+comp, actual col = (l>>3)*32 + quad*8 + (l&7)
    // round 1: xor 1, keep (n&1)? l in [16,32) : [0,16)
    float4 q[4];
#pragma unroll
    for (int p = 0; p < 4; ++p) {
        const float4 keep = (n & 1) ? pacc[p + 4] : pacc[p];
        const float4 send = (n & 1) ? pacc[p] : pacc[p + 4];
        float4 rcv;
        rcv.x = __shfl_xor(send.x, 1, 64);
        rcv.y = __shfl_xor(send.y, 1, 64);
        rcv.z = __shfl_xor(send.z, 1, 64);
        rcv.w = __shfl_xor(send.w, 1, 64);
        q[p].x = keep.x + rcv.x; q[p].y = keep.y + rcv.y;
        q[p].z = keep.z + rcv.z; q[p].w = keep.w + rcv.w;
    }
    // round 2: xor 2, keep (n&2)? upper 8 : lower 8
    float4 r2[2];
#pragma unroll
    for (int p = 0; p < 2; ++p) {
        const float4 keep = (n & 2) ? q[p + 2] : q[p];
        const float4 send = (n & 2) ? q[p] : q[p + 2];
        float4 rcv;
        rcv.x = __shfl_xor(send.x, 2, 64);
        rcv.y = __shfl_xor(send.y, 2, 64);
        rcv.z = __shfl_xor(send.z, 2, 64);
        rcv.w = __shfl_xor(send.w, 2, 64);
        r2[p].x = keep.x + rcv.x; r2[p].y = keep.y + rcv.y;
        r2[p].z = keep.z + rcv.z; r2[p].w = keep.w + rcv.w;
    }
    // round 3: xor 4, keep one float4
    {
        const float4 keep = (n & 4) ? r2[1] : r2[0];
        const float4 send = (n & 4) ? r2[0] : r2[1];
        float4 rcv;
        rcv.x = __shfl_xor(send.x, 4, 64);
        rcv.y = __shfl_xor(send.y, 4, 64);
        rcv.z = __shfl_xor(send.z, 4, 64);
        rcv.w = __shfl_xor(send.w, 4, 64);
        r2[0].x = keep.x + rcv.x; r2[0].y = keep.y + rcv.y;
        r2[0].z = keep.z + rcv.z; r2[0].w = keep.w + rcv.w;
    }
    // round 4: xor 8, keep float2
    const float kx = (n & 8) ? r2[0].z : r2[0].x;
    const float ky = (n & 8) ? r2[0].w : r2[0].y;
    const float sx = (n & 8) ? r2[0].x : r2[0].z;
    const float sy = (n & 8) ? r2[0].y : r2[0].w;
    const float S0 = kx + __shfl_xor(sx, 8, 64);
    const float S1 = ky + __shfl_xor(sy, 8, 64);

    // this lane's two unique output columns
    const int co  = (n & 1) * 16 + (n & 2) * 4 + (n & 4) + ((n >> 3) << 1);
    const int col = (co >> 3) * 32 + quad * 8 + (co & 7);

    // fused divide + LayerNorm (each col counted exactly once across the wave)
    float s1 = S0 + S1;
    float s2 = S0 * S0 + S1 * S1;
    float sw = swl;   // wave-sum = 4 * sum(weights)
#pragma unroll
    for (int off = 32; off; off >>= 1) {
        s1 += __shfl_xor(s1, off, 64);
        s2 += __shfl_xor(s2, off, 64);
        sw += __shfl_xor(sw, off, 64);
    }
    const float inv = 1.0f / (0.25f * sw + 1e-8f);
    const float a0 = S0 * inv, a1 = S1 * inv;
    const float mu = s1 * inv * (1.0f / MDIM);
    const float var = s2 * inv * inv * (1.0f / MDIM) - mu * mu;
    const float rs = rsqrtf(var + 1e-5f);
    const float2 gm = *(const float2*)(gamma + col);
    const float2 bt = *(const float2*)(beta + col);
    float2 o;
    o.x = (a0 - mu) * rs * gm.x + bt.x;
    o.y = (a1 - mu) * rs * gm.y + bt.y;
    *(float2*)(out + (long)node * MDIM + col) = o;
}

extern "C" void kernel_launch(void* const* d_in, const int* in_sizes, int n_in,
                              void* d_out, int out_size, void* d_ws, size_t ws_size,
                              hipStream_t stream) {
    const float* msgs  = (const float*)d_in[0];
    const int*   tgt   = (const int*)d_in[1];
    const float* feats = (const float*)d_in[2];
    const float* W1    = (const float*)d_in[4];
    const float* b1    = (const float*)d_in[5];
    const float* W2    = (const float*)d_in[6];
    const float* gamma = (const float*)d_in[7];
    const float* beta  = (const float*)d_in[8];
    float* out = (float*)d_out;

    char* ws = (char*)d_ws;
    short* bpack   = (short*)(ws + 0);                 //  16 KB
    float* w1dt    = (float*)(ws + (32 << 10));        //  32 KB
    int*   counts  = (int*)  (ws + (64 << 10));        // 200 KB
    int*   offsets = (int*)  (ws + (320 << 10));       // 200 KB
    int*   cursor  = (int*)  (ws + (576 << 10));       // 200 KB
    int*   bsums   = (int*)  (ws + (832 << 10));       //   1 KB
    int*   eidx    = (int*)  (ws + (4 << 20));         // 2.56 MB
    float* g       = (float*)(ws + (8 << 20));         // 12.8 MB

    hipMemsetAsync(counts, 0, NNODES * sizeof(int), stream);

    k0_prep<<<64, 256, 0, stream>>>(W1, bpack, w1dt);
    khist<<<(EDGES + 255) / 256, 256, 0, stream>>>(tgt, counts);
    kg_nodes<<<(NNODES + 255) / 256, 256, 0, stream>>>(feats, w1dt, b1, g);
    const int nblk = (NNODES + 255) / 256;
    kscan_local<<<nblk, 256, 0, stream>>>(counts, offsets, bsums);
    kscan_blk<<<1, 256, 0, stream>>>(bsums, nblk);
    kscan_fix<<<nblk, 256, 0, stream>>>(offsets, bsums, counts, cursor);
    kscatter<<<(EDGES + 255) / 256, 256, 0, stream>>>(tgt, cursor, eidx);
    kfused<<<(NNODES + 3) / 4, 256, 0, stream>>>(msgs, eidx, offsets, bpack, g, W2, gamma, beta, out);
}

// Round 3
// 632.303 us; speedup vs baseline: 1.3510x; 1.3510x over previous
//
#include <hip/hip_runtime.h>
#include <hip/hip_bf16.h>

#define EDGES   640000
#define NNODES  50000
#define MDIM    128
#define HDIM    64
#define XSTR    36    // padded LDS stride (floats) for f32 staging kernels

typedef __attribute__((ext_vector_type(8))) short bshort8;  // 8 bf16 = 4 VGPRs
typedef __attribute__((ext_vector_type(4))) float f32x4;    // MFMA acc

__device__ __forceinline__ short f2bf(float f) {
    __hip_bfloat16 h = __float2bfloat16(f);
    return *reinterpret_cast<short*>(&h);
}

// exact-gelu via Abramowitz-Stegun 7.1.26 erf approx (|err| < 1.5e-7)
__device__ __forceinline__ float gelu_fast(float h) {
    const float x  = h * 0.70710678118654752f;
    const float ax = fabsf(x);
    const float t  = __builtin_amdgcn_rcpf(fmaf(0.3275911f, ax, 1.0f));
    float p = fmaf(1.061405429f, t, -1.453152027f);
    p = fmaf(p, t,  1.421413741f);
    p = fmaf(p, t, -0.284496736f);
    p = fmaf(p, t,  0.254829592f);
    p *= t;
    const float e = __expf(-x * x);
    float er = fmaf(-p, e, 1.0f);
    er = (x < 0.0f) ? -er : er;
    return 0.5f * h * (1.0f + er);
}

// ---------------- K0: pack W1 message-half into bf16 MFMA B-fragment layout (bpack),
//                  and W1 feature-half transposed f32 (w1dt) for kg_nodes.
__global__ void k0_prep(const float* __restrict__ w1,
                        short* __restrict__ bpack, float* __restrict__ w1dt) {
    const int i = blockIdx.x * 256 + threadIdx.x;   // 0..16383
    if (i < 8192) {
        const int ii   = i & 7;
        const int lane = (i >> 3) & 63;
        const int jtkc = i >> 9;            // kc*4 + jt
        const int kc = jtkc >> 2, jt = jtkc & 3;
        const int j = jt * 16 + (lane & 15);
        const int k = kc * 32 + (lane >> 4) * 8 + ii;
        bpack[i] = f2bf(w1[j * 256 + k]);
    } else if (i < 16384) {
        const int t = i - 8192;             // w1dt[k][j] = W1[j][128+k]
        const int k = t >> 6, j = t & 63;
        w1dt[t] = w1[j * 256 + 128 + k];
    }
}

// ---------------- KG: g[n][j] = b1[j] + sum_k feats[n][k]*W1d[j][k]  (f32 FMA, lane-per-node)
__global__ __launch_bounds__(256, 4) void kg_nodes(
    const float* __restrict__ feats, const float* __restrict__ w1dt,
    const float* __restrict__ b1, float* __restrict__ g)
{
    __shared__ float xs[4][64 * XSTR];
    const int wv = threadIdx.x >> 6, L = threadIdx.x & 63;
    const long base = ((long)blockIdx.x * 4 + wv) * 64;
    float* xb = xs[wv];
    float h[HDIM];
#pragma unroll
    for (int j = 0; j < HDIM; ++j) h[j] = 0.0f;
    const int gq = L >> 3, sub = L & 7;
    for (int c = 0; c < 4; ++c) {
        const int col0 = c * 32;
#pragma unroll
        for (int r = 0; r < 8; ++r) {
            long row = base + gq + 8 * r;
            if (row > NNODES - 1) row = NNODES - 1;
            float4 v = *(const float4*)(feats + row * MDIM + col0 + sub * 4);
            *(float4*)(xb + (gq + 8 * r) * XSTR + sub * 4) = v;
        }
        __syncthreads();
        for (int k4 = 0; k4 < 8; ++k4) {
            const float4 xv = *(const float4*)(xb + L * XSTR + 4 * k4);
            const float* colw = w1dt + (c * 32 + 4 * k4) * HDIM;
            const float xa[4] = {xv.x, xv.y, xv.z, xv.w};
#pragma unroll
            for (int kk = 0; kk < 4; ++kk) {
                const float xk = xa[kk];
#pragma unroll
                for (int j = 0; j < HDIM; ++j)
                    h[j] = fmaf(colw[kk * HDIM + j], xk, h[j]);
            }
        }
        __syncthreads();
    }
    const long row = base + L;
    if (row < NNODES) {
        float* gp = g + row * HDIM;
#pragma unroll
        for (int j4 = 0; j4 < 16; ++j4) {
            float4 b4 = *(const float4*)(b1 + 4 * j4);
            float4 o;
            o.x = h[4 * j4 + 0] + b4.x; o.y = h[4 * j4 + 1] + b4.y;
            o.z = h[4 * j4 + 2] + b4.z; o.w = h[4 * j4 + 3] + b4.w;
            *(float4*)(gp + 4 * j4) = o;
        }
    }
}

// ---------------- K1: streaming edge MLP, NO LDS / NO barrier.
// Wave handles 16 dense edges; lane (n,quad) loads row base+n's quad-segments
// directly (its exact MFMA A-frag data), f2bf in-register, 16 MFMAs.
// Epilogue: +g[tgt] gather (L2/L3), gelu_fast, dot w2 (in-group shfl reduce),
// sigmoid -> weights; in-degree histogram via atomicAdd.
__global__ __launch_bounds__(256) void k1_weights(
    const float* __restrict__ msgs, const int* __restrict__ tgt,
    const short* __restrict__ bpack, const float* __restrict__ g,
    const float* __restrict__ w2, float* __restrict__ weights,
    int* __restrict__ counts)
{
    const int wv = threadIdx.x >> 6, L = threadIdx.x & 63;
    const long base = ((long)blockIdx.x * 4 + wv) * 16;
    const int n = L & 15, quad = L >> 4;
    const bshort8* bp = (const bshort8*)bpack;

    // dense row base+n, this quad's 8-float segment of each 32-col chunk
    const float* rp = msgs + (base + n) * MDIM + quad * 8;
    float4 v[8];
#pragma unroll
    for (int kc = 0; kc < 4; ++kc) {
        v[2 * kc]     = *(const float4*)(rp + kc * 32);
        v[2 * kc + 1] = *(const float4*)(rp + kc * 32 + 4);
    }

    float w2v[4];
#pragma unroll
    for (int jt = 0; jt < 4; ++jt) w2v[jt] = w2[jt * 16 + n];

    f32x4 hacc[4];
#pragma unroll
    for (int jt = 0; jt < 4; ++jt) hacc[jt] = (f32x4){0.f, 0.f, 0.f, 0.f};
#pragma unroll
    for (int kc = 0; kc < 4; ++kc) {
        const float4 va = v[2 * kc], vb = v[2 * kc + 1];
        bshort8 a;
        a[0] = f2bf(va.x); a[1] = f2bf(va.y); a[2] = f2bf(va.z); a[3] = f2bf(va.w);
        a[4] = f2bf(vb.x); a[5] = f2bf(vb.y); a[6] = f2bf(vb.z); a[7] = f2bf(vb.w);
#pragma unroll
        for (int jt = 0; jt < 4; ++jt)
            hacc[jt] = __builtin_amdgcn_mfma_f32_16x16x32_bf16(a, bp[(kc * 4 + jt) * 64 + L], hacc[jt], 0, 0, 0);
    }

    // epilogue: lane holds h[edge = quad*4+r][j = jt*16+n]
#pragma unroll
    for (int r = 0; r < 4; ++r) {
        const long e = base + quad * 4 + r;
        const int t = tgt[e];
        const float* gp = g + (long)t * HDIM;
        float raw = 0.0f;
#pragma unroll
        for (int jt = 0; jt < 4; ++jt) {
            const float hj = hacc[jt][r] + gp[jt * 16 + n];
            raw = fmaf(gelu_fast(hj), w2v[jt], raw);
        }
#pragma unroll
        for (int off = 1; off < 16; off <<= 1)
            raw += __shfl_xor(raw, off, 64);
        if (n == r) {
            weights[e] = 1.0f / (1.0f + __expf(-raw));
            atomicAdd(&counts[t], 1);
        }
    }
}

// ---------------- CSR build
__global__ void kscan_local(const int* __restrict__ counts, int* __restrict__ offsets,
                            int* __restrict__ blocksums) {
    __shared__ int s[256];
    const int tid = threadIdx.x;
    const int i = blockIdx.x * 256 + tid;
    int v = (i < NNODES) ? counts[i] : 0;
    s[tid] = v;
    __syncthreads();
    for (int d = 1; d < 256; d <<= 1) {
        int t = (tid >= d) ? s[tid - d] : 0;
        __syncthreads();
        s[tid] += t;
        __syncthreads();
    }
    if (i < NNODES) offsets[i] = s[tid];
    if (tid == 255) blocksums[blockIdx.x] = s[255];
}

__global__ void kscan_blk(int* __restrict__ blocksums, int nblk) {
    __shared__ int s[256];
    const int tid = threadIdx.x;
    int v = (tid < nblk) ? blocksums[tid] : 0;
    s[tid] = v;
    __syncthreads();
    for (int d = 1; d < 256; d <<= 1) {
        int t = (tid >= d) ? s[tid - d] : 0;
        __syncthreads();
        s[tid] += t;
        __syncthreads();
    }
    if (tid < nblk) blocksums[tid] = s[tid] - v;
}

__global__ void kscan_fix(int* __restrict__ offsets, const int* __restrict__ blocksums,
                          const int* __restrict__ counts, int* __restrict__ cursor) {
    const int i = blockIdx.x * 256 + threadIdx.x;
    if (i < NNODES) {
        const int incl = offsets[i] + blocksums[i >> 8];
        offsets[i] = incl;
        cursor[i] = incl - counts[i];
    }
}

__global__ void kscatter(const int* __restrict__ tgt, int* __restrict__ cursor,
                         int* __restrict__ eidx) {
    const int e = blockIdx.x * 256 + threadIdx.x;
    if (e < EDGES) {
        const int pos = atomicAdd(&cursor[tgt[e]], 1);
        eidx[pos] = e;
    }
}

// ---------------- K_AGG: wave-per-node. float4/lane gather: 2 msg rows per
// iteration (lanes 0-31 row 2i, lanes 32-63 row 2i+1), per-lane float4 column
// accumulator, one xor-32 combine at the end; fused divide + LayerNorm.
__global__ __launch_bounds__(256) void kagg(
    const float* __restrict__ msgs, const float* __restrict__ wts,
    const int* __restrict__ eidx, const int* __restrict__ offsets,
    const float* __restrict__ gamma, const float* __restrict__ beta,
    float* __restrict__ out)
{
    const int L = threadIdx.x & 63, wv = threadIdx.x >> 6;
    const int node = blockIdx.x * 4 + wv;
    if (node >= NNODES) return;
    const int end = offsets[node];
    const int beg = (node == 0) ? 0 : offsets[node - 1];

    const int c0 = 4 * (L & 31);
    const int half = L >> 5;
    float4 acc = {0.0f, 0.0f, 0.0f, 0.0f};
    float swl = 0.0f;

    for (int b = beg; b < end; b += 64) {
        int m = end - b; if (m > 64) m = 64;
        int eid = 0; float w = 0.0f;
        if (L < m) { eid = eidx[b + L]; w = wts[eid]; }
        swl += w;
        const int nit = (m + 1) >> 1;
        for (int i = 0; i < nit; ++i) {
            const int   e0 = __shfl(eid, 2 * i, 64);
            const int   e1 = __shfl(eid, 2 * i + 1, 64);
            const float w0 = __shfl(w,   2 * i, 64);
            const float w1 = __shfl(w,   2 * i + 1, 64);
            const int   er = half ? e1 : e0;
            const float wr = half ? w1 : w0;
            const float4 mv = *(const float4*)(msgs + (long)er * MDIM + c0);
            acc.x = fmaf(mv.x, wr, acc.x);
            acc.y = fmaf(mv.y, wr, acc.y);
            acc.z = fmaf(mv.z, wr, acc.z);
            acc.w = fmaf(mv.w, wr, acc.w);
        }
    }

    // combine the two halves (each col now complete in both halves)
    acc.x += __shfl_xor(acc.x, 32, 64);
    acc.y += __shfl_xor(acc.y, 32, 64);
    acc.z += __shfl_xor(acc.z, 32, 64);
    acc.w += __shfl_xor(acc.w, 32, 64);

    float s1 = acc.x + acc.y + acc.z + acc.w;
    float s2 = acc.x * acc.x + acc.y * acc.y + acc.z * acc.z + acc.w * acc.w;
#pragma unroll
    for (int off = 16; off; off >>= 1) {
        s1 += __shfl_xor(s1, off, 64);
        s2 += __shfl_xor(s2, off, 64);
    }
#pragma unroll
    for (int off = 32; off; off >>= 1)
        swl += __shfl_xor(swl, off, 64);

    const float inv = 1.0f / (swl + 1e-8f);
    const float mu = s1 * inv * (1.0f / MDIM);
    const float var = s2 * inv * inv * (1.0f / MDIM) - mu * mu;
    const float rs = rsqrtf(var + 1e-5f);

    if (half == 0) {
        const float4 gm = *(const float4*)(gamma + c0);
        const float4 bt = *(const float4*)(beta + c0);
        float4 o;
        o.x = (acc.x * inv - mu) * rs * gm.x + bt.x;
        o.y = (acc.y * inv - mu) * rs * gm.y + bt.y;
        o.z = (acc.z * inv - mu) * rs * gm.z + bt.z;
        o.w = (acc.w * inv - mu) * rs * gm.w + bt.w;
        *(float4*)(out + (long)node * MDIM + c0) = o;
    }
}

extern "C" void kernel_launch(void* const* d_in, const int* in_sizes, int n_in,
                              void* d_out, int out_size, void* d_ws, size_t ws_size,
                              hipStream_t stream) {
    const float* msgs  = (const float*)d_in[0];
    const int*   tgt   = (const int*)d_in[1];
    const float* feats = (const float*)d_in[2];
    const float* W1    = (const float*)d_in[4];
    const float* b1    = (const float*)d_in[5];
    const float* W2    = (const float*)d_in[6];
    const float* gamma = (const float*)d_in[7];
    const float* beta  = (const float*)d_in[8];
    float* out = (float*)d_out;

    char* ws = (char*)d_ws;
    short* bpack   = (short*)(ws + 0);                 //  16 KB
    float* w1dt    = (float*)(ws + (32 << 10));        //  32 KB
    int*   counts  = (int*)  (ws + (64 << 10));        // 200 KB
    int*   offsets = (int*)  (ws + (320 << 10));       // 200 KB
    int*   cursor  = (int*)  (ws + (576 << 10));       // 200 KB
    int*   bsums   = (int*)  (ws + (832 << 10));       //   1 KB
    float* wts     = (float*)(ws + (1 << 20));         // 2.56 MB
    int*   eidx    = (int*)  (ws + (4 << 20));         // 2.56 MB
    float* g       = (float*)(ws + (8 << 20));         // 12.8 MB

    hipMemsetAsync(counts, 0, NNODES * sizeof(int), stream);

    k0_prep<<<64, 256, 0, stream>>>(W1, bpack, w1dt);
    kg_nodes<<<(NNODES + 255) / 256, 256, 0, stream>>>(feats, w1dt, b1, g);
    k1_weights<<<EDGES / 64, 256, 0, stream>>>(msgs, tgt, bpack, g, W2, wts, counts);
    const int nblk = (NNODES + 255) / 256;
    kscan_local<<<nblk, 256, 0, stream>>>(counts, offsets, bsums);
    kscan_blk<<<1, 256, 0, stream>>>(bsums, nblk);
    kscan_fix<<<nblk, 256, 0, stream>>>(offsets, bsums, counts, cursor);
    kscatter<<<(EDGES + 255) / 256, 256, 0, stream>>>(tgt, cursor, eidx);
    kagg<<<(NNODES + 3) / 4, 256, 0, stream>>>(msgs, wts, eidx, offsets, gamma, beta, out);
}